// Round 1
// 303.527 us; speedup vs baseline: 1.0272x; 1.0272x over previous
//
#include <hip/hip_runtime.h>
#include <stdint.h>

// ---------- types ----------
typedef _Float16 half8 __attribute__((ext_vector_type(8)));   // 8 fp16 (4 VGPRs) MFMA frag
typedef __attribute__((ext_vector_type(4))) float f32x4;      // MFMA acc
typedef __attribute__((ext_vector_type(4))) unsigned short us4;

__device__ __forceinline__ unsigned short f2h(float f) {
  _Float16 h = (_Float16)f;              // v_cvt_f16_f32, RTE
  return __builtin_bit_cast(unsigned short, h);
}

// async global->LDS, 16B per lane (dst = wave-uniform base + lane*16)
__device__ __forceinline__ void async_cp16(const unsigned short* g, unsigned short* l) {
  __builtin_amdgcn_global_load_lds(
      (const __attribute__((address_space(1))) void*)g,
      (__attribute__((address_space(3))) void*)l, 16, 0, 0);
}

// =====================================================================
// 256x256 tile GEMM core, C[m0:+256, n0:+256] = A[M,1024] * B[N,1024]^T
// fp16 in, fp32 acc. 512 threads = 8 waves (2M x 4N), per-wave 128x64.
// 8-phase/2-K-tile schedule (T3+T4): per K-tile (BK=64) 4 phases, each
//   {ds_read frags | stage one k-half half-tile | s_barrier | lgkmcnt(0)
//    | setprio(1) 16xMFMA setprio(0) | s_barrier}
// Counted vmcnt(4) once per K-tile (never 0 in steady state): 2 half-tiles
// (4 global_load_lds) stay in flight across barriers.
// LDS: [buf(2)][A/B][kh(2)][256 rows x 32 cols] = 128 KiB total.
// Swizzle: within a 64B row-half, 16B chunk kq lives at slot (kq+(r>>1))&3.
//   Inverse permutation applied to the GLOBAL source addr (linear LDS dst,
//   m173 pattern); reads are 16B-aligned ds_read_b128, worst 2-way alias.
// Staging region-recycle safety: kh0 of current buf is dead after phase 2
// (phases 3-4 read only kh1), so phases 3-4 stage K-tile j+2's kh0 there.
// =====================================================================

#define MFMA_QUAD(IOFF) \
  _Pragma("unroll") \
  for (int ii = 0; ii < 4; ++ii) { \
    _Pragma("unroll") \
    for (int jj = 0; jj < 4; ++jj) \
      acc[(IOFF) + ii][jj] = __builtin_amdgcn_mfma_f32_16x16x32_f16( \
          a[ii], b[jj], acc[(IOFF) + ii][jj], 0, 0, 0); \
  }

// One K-tile (4 phases). BUF = j&1 (literal). J = K-tile index (runtime).
// ST1: stage (J+1) kh1 halves (phases 1-2, into other buf).
// ST2: stage (J+2) kh0 halves (phases 3-4, into THIS buf's dead kh0).
// WAITN: 4 = steady-state counted wait, 0 = tail drain, -1 = none.
#define KTILE(BUF, J, ST1, ST2, WAITN) { \
  /* ---- phase 1: quad (m-half 0, k-half 0) ---- */ \
  _Pragma("unroll") \
  for (int jj = 0; jj < 4; ++jj) b[jj] = *(const half8*)&lds[(BUF)*32768 + 16384 + offB[jj]]; \
  _Pragma("unroll") \
  for (int ii = 0; ii < 4; ++ii) a[ii] = *(const half8*)&lds[(BUF)*32768 + offA[ii]]; \
  if (ST1) { const unsigned short* s_ = sA + (J + 1) * 64 + 32; \
    async_cp16(s_ + g0, lds + (1 - (BUF)) * 32768 + 8192 + d0); \
    async_cp16(s_ + g1, lds + (1 - (BUF)) * 32768 + 8192 + d1); } \
  __builtin_amdgcn_s_barrier(); \
  asm volatile("s_waitcnt lgkmcnt(0)"); \
  __builtin_amdgcn_s_setprio(1); \
  MFMA_QUAD(0) \
  __builtin_amdgcn_s_setprio(0); \
  __builtin_amdgcn_s_barrier(); \
  /* ---- phase 2: quad (m-half 1, k-half 0); B frags reused ---- */ \
  _Pragma("unroll") \
  for (int ii = 0; ii < 4; ++ii) a[ii] = *(const half8*)&lds[(BUF)*32768 + offA[4 + ii]]; \
  if (ST1) { const unsigned short* s_ = sB + (J + 1) * 64 + 32; \
    async_cp16(s_ + g0, lds + (1 - (BUF)) * 32768 + 24576 + d0); \
    async_cp16(s_ + g1, lds + (1 - (BUF)) * 32768 + 24576 + d1); } \
  __builtin_amdgcn_s_barrier(); \
  asm volatile("s_waitcnt lgkmcnt(0)"); \
  __builtin_amdgcn_s_setprio(1); \
  MFMA_QUAD(4) \
  __builtin_amdgcn_s_setprio(0); \
  __builtin_amdgcn_s_barrier(); \
  /* ---- phase 3: quad (m-half 0, k-half 1); kh0 now dead -> stage (J+2) A-kh0 ---- */ \
  _Pragma("unroll") \
  for (int jj = 0; jj < 4; ++jj) b[jj] = *(const half8*)&lds[(BUF)*32768 + 24576 + offB[jj]]; \
  _Pragma("unroll") \
  for (int ii = 0; ii < 4; ++ii) a[ii] = *(const half8*)&lds[(BUF)*32768 + 8192 + offA[ii]]; \
  if (ST2) { const unsigned short* s_ = sA + (J + 2) * 64; \
    async_cp16(s_ + g0, lds + (BUF) * 32768 + d0); \
    async_cp16(s_ + g1, lds + (BUF) * 32768 + d1); } \
  __builtin_amdgcn_s_barrier(); \
  asm volatile("s_waitcnt lgkmcnt(0)"); \
  __builtin_amdgcn_s_setprio(1); \
  MFMA_QUAD(0) \
  __builtin_amdgcn_s_setprio(0); \
  __builtin_amdgcn_s_barrier(); \
  /* ---- phase 4: quad (m-half 1, k-half 1); stage (J+2) B-kh0; boundary wait ---- */ \
  _Pragma("unroll") \
  for (int ii = 0; ii < 4; ++ii) a[ii] = *(const half8*)&lds[(BUF)*32768 + 8192 + offA[4 + ii]]; \
  if (ST2) { const unsigned short* s_ = sB + (J + 2) * 64; \
    async_cp16(s_ + g0, lds + (BUF) * 32768 + 16384 + d0); \
    async_cp16(s_ + g1, lds + (BUF) * 32768 + 16384 + d1); } \
  if ((WAITN) == 4)      asm volatile("s_waitcnt vmcnt(4)" ::: "memory"); \
  else if ((WAITN) == 0) asm volatile("s_waitcnt vmcnt(0)" ::: "memory"); \
  __builtin_amdgcn_sched_barrier(0); \
  __builtin_amdgcn_s_barrier(); \
  asm volatile("s_waitcnt lgkmcnt(0)"); \
  __builtin_amdgcn_s_setprio(1); \
  MFMA_QUAD(4) \
  __builtin_amdgcn_s_setprio(0); \
  __builtin_amdgcn_s_barrier(); \
}

template<int EPI>   // 0 = fp32 C, 1 = fp16 C
__device__ __forceinline__ void gemm256_core(
    const unsigned short* __restrict__ pA, const unsigned short* __restrict__ pB,
    void* __restrict__ C0, int m0, int n0, unsigned short* lds)
{
  const int t = threadIdx.x;

  // ---- staging per-thread constants (pid -> (row, slot) -> logical kq) ----
  // physical 16B chunk pid within a (buf,mat,kh) region: r = pid>>2, s = pid&3.
  // logical chunk at slot s of row r: kq = (s - (r>>1)) & 3  (inverse of read swz).
  const int r0 = t >> 2;
  const int kq0 = ((t & 3) - (r0 >> 1)) & 3;
  const int r1 = (512 + t) >> 2;
  const int kq1 = ((t & 3) - (r1 >> 1)) & 3;
  const long g0 = (long)r0 * 1024 + kq0 * 8;   // global elem offset (row-major, K=1024)
  const long g1 = (long)r1 * 1024 + kq1 * 8;
  const int d0 = t * 8;                        // LDS elem offset of chunk pid0 (=t)
  const int d1 = (512 + t) * 8;                // chunk pid1 (=512+t)

  const unsigned short* sA = pA + (long)m0 * 1024;
  const unsigned short* sB = pB + (long)n0 * 1024;

  // ---- MFMA fragment geometry ----
  const int w  = t >> 6;
  const int l  = t & 63;
  const int wm = (w >> 2) * 128;     // 2 m-waves
  const int wn = (w & 3) * 64;       // 4 n-waves
  const int lm = l & 15;
  const int kq = l >> 4;

  // loop-invariant swizzled LDS read offsets (elements, region-relative)
  int offA[8], offB[4];
  #pragma unroll
  for (int i = 0; i < 8; ++i) {
    int r = wm + i * 16 + lm;
    offA[i] = r * 32 + (((kq + (r >> 1)) & 3) * 8);
  }
  #pragma unroll
  for (int j = 0; j < 4; ++j) {
    int r = wn + j * 16 + lm;
    offB[j] = r * 32 + (((kq + (r >> 1)) & 3) * 8);
  }

  f32x4 acc[8][4];
  #pragma unroll
  for (int i = 0; i < 8; ++i)
    #pragma unroll
    for (int j = 0; j < 4; ++j)
      acc[i][j] = (f32x4){0.f, 0.f, 0.f, 0.f};

  half8 a[4], b[4];

  // ---- prologue: stage buf0 {A,B}x{kh0,kh1} + buf1 {A,B} kh0 (12 loads) ----
  async_cp16(sA + g0,      lds + 0     + d0);  async_cp16(sA + g1,      lds + 0     + d1);
  async_cp16(sB + g0,      lds + 16384 + d0);  async_cp16(sB + g1,      lds + 16384 + d1);
  async_cp16(sA + g0 + 32, lds + 8192  + d0);  async_cp16(sA + g1 + 32, lds + 8192  + d1);
  async_cp16(sB + g0 + 32, lds + 24576 + d0);  async_cp16(sB + g1 + 32, lds + 24576 + d1);
  async_cp16(sA + g0 + 64, lds + 32768 + d0);  async_cp16(sA + g1 + 64, lds + 32768 + d1);
  async_cp16(sB + g0 + 64, lds + 49152 + d0);  async_cp16(sB + g1 + 64, lds + 49152 + d1);
  asm volatile("s_waitcnt vmcnt(4)" ::: "memory");   // buf0 fully landed; buf1-kh0 in flight
  __builtin_amdgcn_s_barrier();

  // ---- main loop: K = 1024 -> 16 K-tiles, 2 per unrolled iter ----
  for (int j2 = 0; j2 < 7; ++j2) {
    const int j = j2 * 2;
    KTILE(0, j,     1, 1, 4)
    KTILE(1, j + 1, 1, 1, 4)
  }
  KTILE(0, 14, 1, 0, 0)    // stages (15) kh1; drains everything
  KTILE(1, 15, 0, 0, -1)   // pure compute

  // ---- epilogue. C/D layout (m89-verified): col = lane&15, row = (lane>>4)*4 + reg ----
  const int cr = wm + (l >> 4) * 4;
  const int cc = wn + lm;
  if (EPI == 0) {
    float* C = (float*)C0;
    #pragma unroll
    for (int i = 0; i < 8; ++i)
      #pragma unroll
      for (int jj = 0; jj < 4; ++jj)
        #pragma unroll
        for (int r = 0; r < 4; ++r)
          C[(long)(m0 + cr + i * 16 + r) * 1024 + (n0 + cc + jj * 16)] = acc[i][jj][r];
  } else {
    unsigned short* C = (unsigned short*)C0;
    #pragma unroll
    for (int i = 0; i < 8; ++i)
      #pragma unroll
      for (int jj = 0; jj < 4; ++jj)
        #pragma unroll
        for (int r = 0; r < 4; ++r)
          C[(long)(m0 + cr + i * 16 + r) * 1024 + (n0 + cc + jj * 16)] = f2h(acc[i][jj][r]);
  }
}

// ---------- batched wrapper (QK^T, PV): fp32 C ----------
__global__ __launch_bounds__(512, 2)
void gemm_bt256(const unsigned short* __restrict__ A, const unsigned short* __restrict__ B,
                float* __restrict__ C, long aZ, long bZ, long cZ)
{
  __shared__ __align__(16) unsigned short lds[65536];   // 128 KiB
  // 256 blocks: bijective XCD-chunked swizzle (256 % 8 == 0) -> one batch per XCD
  const int bid = blockIdx.x;
  const int lin = (bid & 7) * 32 + (bid >> 3);
  const long z = lin >> 5;
  const int rr = lin & 31;
  gemm256_core<0>(A + z * aZ, B + z * bZ, (void*)(C + z * cZ),
                  (rr >> 2) * 256, (rr & 3) * 256, lds);
}

// ---------- merged projections: Qproj (256 blocks) + Kproj (128) + Vproj (128) ----------
__global__ __launch_bounds__(512, 2)
void proj_all256(const unsigned short* __restrict__ ch, const unsigned short* __restrict__ qh,
                 const unsigned short* __restrict__ wT,
                 unsigned short* __restrict__ Qf, unsigned short* __restrict__ Kf,
                 unsigned short* __restrict__ Vt)
{
  __shared__ __align__(16) unsigned short lds[65536];   // 128 KiB
  const int bid = blockIdx.x;
  const int lin = (bid & 7) * 64 + (bid >> 3);          // 512 % 8 == 0, bijective
  const long qBatch = 1024l * 1024;

  const unsigned short* pA;
  const unsigned short* pB;
  unsigned short* C;
  int m0, n0;
  if (lin < 256) {                  // Qproj: Q = c @ wq  [16384,1024]
    pA = ch; pB = wT; C = Qf;
    m0 = (lin >> 2) * 256; n0 = (lin & 3) * 256;
  } else if (lin < 384) {           // Kproj: K = q @ wk  [8192,1024]
    int i = lin - 256;
    pA = qh; pB = wT + (1l << 20); C = Kf;
    m0 = (i >> 2) * 256; n0 = (i & 3) * 256;
  } else {                          // Vproj: Vt[z][h,l] = wvT @ q[z]^T  [8][1024,1024]
    int i = lin - 384;
    long z = i >> 4;
    pA = wT + (2l << 20); pB = qh + z * qBatch; C = Vt + z * qBatch;
    m0 = ((i >> 2) & 3) * 256; n0 = (i & 3) * 256;
  }
  gemm256_core<1>(pA, pB, C, m0, n0, lds);
}

// ---------- merged prep: cvt_c (16384 blocks) + cvt_q (8192) + wtrans (3072) ----------
__global__ __launch_bounds__(256)
void prep_all(const float* __restrict__ q, const float* __restrict__ c,
              const float* __restrict__ wq, const float* __restrict__ wk,
              const float* __restrict__ wv,
              unsigned short* __restrict__ qh, unsigned short* __restrict__ ch,
              unsigned short* __restrict__ wT)
{
  __shared__ float tile[32][33];
  const int bid = blockIdx.x;
  const int t = threadIdx.x;

  if (bid < 24576) {                // fp32 -> fp16 convert, 1024 elems/block
    const float* x;
    unsigned short* y;
    long blk;
    if (bid < 16384) { x = c; y = ch; blk = bid; }
    else             { x = q; y = qh; blk = bid - 16384; }
    long i = (blk * 256 + t) * 4;
    float4 v = *(const float4*)(x + i);
    *(us4*)(y + i) = (us4){f2h(v.x), f2h(v.y), f2h(v.z), f2h(v.w)};
  } else {                          // weight transpose + convert
    int i = bid - 24576;
    const int d0 = (i & 31) * 32, h0 = ((i >> 5) & 31) * 32, id = i >> 10;
    const float* W = (id == 0) ? wq : ((id == 1) ? wk : wv);
    unsigned short* WT = wT + (long)id * (1 << 20);
    #pragma unroll
    for (int p = 0; p < 4; ++p) {
      int dl = p * 8 + (t >> 5), hl = t & 31;
      tile[dl][hl] = W[(long)(d0 + dl) * 1024 + h0 + hl];
    }
    __syncthreads();
    #pragma unroll
    for (int p = 0; p < 4; ++p) {
      int hr = p * 8 + (t >> 5), dc = t & 31;
      WT[(long)(h0 + hr) * 1024 + d0 + dc] = f2h(tile[dc][hr]);
    }
  }
}

// ---------- row softmax: S fp32 [rows,1024] -> P fp16 [rows,1024] ----------
__global__ __launch_bounds__(256)
void softmax_rows(const float* __restrict__ S, unsigned short* __restrict__ P)
{
  const long row = blockIdx.x;
  const int t = threadIdx.x;
  float4 v = *(const float4*)(S + row * 1024 + t * 4);
  float m = fmaxf(fmaxf(v.x, v.y), fmaxf(v.z, v.w));
  #pragma unroll
  for (int off = 32; off > 0; off >>= 1) m = fmaxf(m, __shfl_down(m, off));
  __shared__ float red[4], red2[4];
  if ((t & 63) == 0) red[t >> 6] = m;
  __syncthreads();
  m = fmaxf(fmaxf(red[0], red[1]), fmaxf(red[2], red[3]));
  float e0 = __expf(v.x - m), e1 = __expf(v.y - m);
  float e2 = __expf(v.z - m), e3 = __expf(v.w - m);
  float sum = e0 + e1 + e2 + e3;
  #pragma unroll
  for (int off = 32; off > 0; off >>= 1) sum += __shfl_down(sum, off);
  if ((t & 63) == 0) red2[t >> 6] = sum;
  __syncthreads();
  float inv = 1.0f / (red2[0] + red2[1] + red2[2] + red2[3]);
  us4 o = {f2h(e0 * inv), f2h(e1 * inv), f2h(e2 * inv), f2h(e3 * inv)};
  *(us4*)(P + row * 1024 + t * 4) = o;
}

// ---------- host ----------
extern "C" void kernel_launch(void* const* d_in, const int* in_sizes, int n_in,
                              void* d_out, int out_size, void* d_ws, size_t ws_size,
                              hipStream_t stream)
{
  (void)in_sizes; (void)n_in; (void)out_size; (void)ws_size;
  // inputs: q [8,1024,1024], c [8,2048,1024], wq, wk, wv [1024,1024], all fp32
  const float* q  = (const float*)d_in[0];
  const float* c  = (const float*)d_in[1];
  const float* wq = (const float*)d_in[2];
  const float* wk = (const float*)d_in[3];
  const float* wv = (const float*)d_in[4];
  float* out = (float*)d_out;   // [8, 2048, 1024]; also S scratch

  const size_t MB = 1ull << 20;
  const long cBatch = 2048l * 1024;   // c/Q/S/out elems per batch
  const long qBatch = 1024l * 1024;   // q/K/V elems per batch

  char* ws = (char*)d_ws;
  size_t off = 0;
  auto take = [&](size_t bytes) -> unsigned short* {
    unsigned short* p = (unsigned short*)(ws + off);
    off += bytes;
    return p;
  };
  // 118 MB total
  unsigned short* wT = take(6 * MB);    // 3x [1024(h),1024(d)] fp16: wqT, wkT, wvT
  unsigned short* qh = take(16 * MB);   // [8192,1024] fp16
  unsigned short* ch = take(32 * MB);   // [16384,1024] fp16; P aliases after Qproj
  unsigned short* Kf = take(16 * MB);   // [8192,1024] fp16
  unsigned short* Vt = take(16 * MB);   // [8][1024(h),1024(lq)] fp16
  unsigned short* Qf = take(32 * MB);   // [16384,1024] fp16
  unsigned short* Pf = ch;              // [16384,1024] fp16 (c-f16 dead after Qproj)

  // 1) prep: c->fp16, q->fp16, weights transpose->fp16
  prep_all<<<27648, 256, 0, stream>>>(q, c, wq, wk, wv, qh, ch, wT);
  // 2) all three projections, 256^2 8-phase core (512 blocks, 1/CU, 2 rounds)
  proj_all256<<<512, 512, 0, stream>>>(ch, qh, wT, Qf, Kf, Vt);
  // 3) QK^T: S[c,qt] = sum_h Q[c,h] * K[qt,h]  (S fp32 in d_out region)
  gemm_bt256<<<256, 512, 0, stream>>>(Qf, Kf, out, cBatch, qBatch, cBatch);
  // 4) softmax rows -> P fp16
  softmax_rows<<<16384, 256, 0, stream>>>(out, Pf);
  // 5) PV: out[c,h] = sum_qt P[c,qt] * Vt[h,qt]
  gemm_bt256<<<256, 512, 0, stream>>>(Pf, Vt, out, cBatch, qBatch, cBatch);
}

// Round 2
// 301.639 us; speedup vs baseline: 1.0337x; 1.0063x over previous
//
#include <hip/hip_runtime.h>
#include <stdint.h>

// ---------- types ----------
typedef _Float16 half8 __attribute__((ext_vector_type(8)));   // 8 fp16 (4 VGPRs) MFMA frag
typedef __attribute__((ext_vector_type(4))) float f32x4;      // MFMA acc
typedef __attribute__((ext_vector_type(4))) unsigned short us4;

__device__ __forceinline__ unsigned short f2h(float f) {
  _Float16 h = (_Float16)f;              // v_cvt_f16_f32, RTE
  return __builtin_bit_cast(unsigned short, h);
}

// async global->LDS, 16B per lane (dst = wave-uniform base + lane*16)
__device__ __forceinline__ void async_cp16(const unsigned short* g, unsigned short* l) {
  __builtin_amdgcn_global_load_lds(
      (const __attribute__((address_space(1))) void*)g,
      (__attribute__((address_space(3))) void*)l, 16, 0, 0);
}

// =====================================================================
// 256x256 tile GEMM core, C[m0:+256, n0:+256] = A[M,1024] * B[N,1024]^T
// fp16 in, fp32 acc. 512 threads = 8 waves (2M x 4N), per-wave 128x64.
//
// Round-2 restructure: ONE barrier per phase; each phase is a single
// compiler-scheduled region [ds_read frags + MFMA quad + staging issue].
// No explicit lgkmcnt — every ds_read has an MFMA consumer in-region, so
// the compiler emits fine-grained partial lgkm waits and interleaves
// MFMA with in-flight reads (the overlap the round-1 lockstep destroyed).
// Regions sealed with asm memory fences around raw s_barrier so no memory
// op crosses a phase boundary (hoist/sink both blocked).
//
// LDS: [buf(2)][A/B][kh(2)][256 rows x 32 cols] = 128 KiB total.
// Swizzle: within a 64B row-half, 16B chunk kq lives at slot (kq+(r>>1))&3;
// inverse applied to global source addr (linear LDS dst). 0 conflicts
// (round-1 measured).
// Counted vmcnt(4) once per K-tile (ledger verified in round 1):
//   ST1 (phases 1-2): stage (J+1) kh1 into other buf.
//   ST2 (phases 3-4): stage (J+2) kh0 into THIS buf's dead kh0 region
//   (kh0 last read in phase 2; phase-3 barrier orders it).
// =====================================================================

#define BARF() { asm volatile("" ::: "memory"); \
                 __builtin_amdgcn_s_barrier(); \
                 asm volatile("" ::: "memory"); }

#define MFMA_QUAD(IOFF) \
  _Pragma("unroll") \
  for (int ii = 0; ii < 4; ++ii) { \
    _Pragma("unroll") \
    for (int jj = 0; jj < 4; ++jj) \
      acc[(IOFF) + ii][jj] = __builtin_amdgcn_mfma_f32_16x16x32_f16( \
          a[ii], b[jj], acc[(IOFF) + ii][jj], 0, 0, 0); \
  }

// One K-tile (4 single-barrier phases). BUF = j&1 (literal). J = runtime.
// WAITN: 4 = steady-state counted wait, 0 = tail drain, -1 = none.
#define KTILE(BUF, J, ST1, ST2, WAITN) { \
  /* ---- P1: quad (m-half 0, k-half 0) + stage (J+1) A-kh1 ---- */ \
  BARF(); \
  { \
    _Pragma("unroll") \
    for (int jj = 0; jj < 4; ++jj) b[jj] = *(const half8*)&lds[(BUF)*32768 + 16384 + offB[jj]]; \
    _Pragma("unroll") \
    for (int ii = 0; ii < 4; ++ii) a[ii] = *(const half8*)&lds[(BUF)*32768 + offA[ii]]; \
    if (ST1) { const unsigned short* s_ = sA + (J + 1) * 64 + 32; \
      async_cp16(s_ + g0, lds + (1 - (BUF)) * 32768 + 8192 + d0); \
      async_cp16(s_ + g1, lds + (1 - (BUF)) * 32768 + 8192 + d1); } \
    MFMA_QUAD(0) \
  } \
  /* ---- P2: quad (m-half 1, k-half 0); B frags reused; stage (J+1) B-kh1 ---- */ \
  BARF(); \
  { \
    _Pragma("unroll") \
    for (int ii = 0; ii < 4; ++ii) a[ii] = *(const half8*)&lds[(BUF)*32768 + offA[4 + ii]]; \
    if (ST1) { const unsigned short* s_ = sB + (J + 1) * 64 + 32; \
      async_cp16(s_ + g0, lds + (1 - (BUF)) * 32768 + 24576 + d0); \
      async_cp16(s_ + g1, lds + (1 - (BUF)) * 32768 + 24576 + d1); } \
    MFMA_QUAD(4) \
  } \
  /* ---- P3: quad (m-half 0, k-half 1); kh0 dead -> stage (J+2) A-kh0 here ---- */ \
  BARF(); \
  { \
    _Pragma("unroll") \
    for (int jj = 0; jj < 4; ++jj) b[jj] = *(const half8*)&lds[(BUF)*32768 + 24576 + offB[jj]]; \
    _Pragma("unroll") \
    for (int ii = 0; ii < 4; ++ii) a[ii] = *(const half8*)&lds[(BUF)*32768 + 8192 + offA[ii]]; \
    if (ST2) { const unsigned short* s_ = sA + (J + 2) * 64; \
      async_cp16(s_ + g0, lds + (BUF) * 32768 + d0); \
      async_cp16(s_ + g1, lds + (BUF) * 32768 + d1); } \
    MFMA_QUAD(0) \
  } \
  /* ---- P4: quad (m-half 1, k-half 1); stage (J+2) B-kh0; boundary vmcnt ---- */ \
  BARF(); \
  { \
    _Pragma("unroll") \
    for (int ii = 0; ii < 4; ++ii) a[ii] = *(const half8*)&lds[(BUF)*32768 + 8192 + offA[4 + ii]]; \
    if (ST2) { const unsigned short* s_ = sB + (J + 2) * 64; \
      async_cp16(s_ + g0, lds + (BUF) * 32768 + 16384 + d0); \
      async_cp16(s_ + g1, lds + (BUF) * 32768 + 16384 + d1); } \
    MFMA_QUAD(4) \
  } \
  if ((WAITN) == 4)      asm volatile("s_waitcnt vmcnt(4)" ::: "memory"); \
  else if ((WAITN) == 0) asm volatile("s_waitcnt vmcnt(0)" ::: "memory"); \
}

template<int EPI>   // 0 = fp32 C, 1 = fp16 C
__device__ __forceinline__ void gemm256_core(
    const unsigned short* __restrict__ pA, const unsigned short* __restrict__ pB,
    void* __restrict__ C0, int m0, int n0, unsigned short* lds)
{
  const int t = threadIdx.x;

  // ---- staging per-thread constants (pid -> (row, slot) -> logical kq) ----
  // physical 16B chunk pid within a (buf,mat,kh) region: r = pid>>2, s = pid&3.
  // logical chunk at slot s of row r: kq = (s - (r>>1)) & 3  (inverse of read swz).
  const int r0 = t >> 2;
  const int kq0 = ((t & 3) - (r0 >> 1)) & 3;
  const int r1 = (512 + t) >> 2;
  const int kq1 = ((t & 3) - (r1 >> 1)) & 3;
  const long g0 = (long)r0 * 1024 + kq0 * 8;   // global elem offset (row-major, K=1024)
  const long g1 = (long)r1 * 1024 + kq1 * 8;
  const int d0 = t * 8;                        // LDS elem offset of chunk pid0 (=t)
  const int d1 = (512 + t) * 8;                // chunk pid1 (=512+t)

  const unsigned short* sA = pA + (long)m0 * 1024;
  const unsigned short* sB = pB + (long)n0 * 1024;

  // ---- MFMA fragment geometry ----
  const int w  = t >> 6;
  const int l  = t & 63;
  const int wm = (w >> 2) * 128;     // 2 m-waves
  const int wn = (w & 3) * 64;       // 4 n-waves
  const int lm = l & 15;
  const int kq = l >> 4;

  // loop-invariant swizzled LDS read offsets (elements, region-relative)
  int offA[8], offB[4];
  #pragma unroll
  for (int i = 0; i < 8; ++i) {
    int r = wm + i * 16 + lm;
    offA[i] = r * 32 + (((kq + (r >> 1)) & 3) * 8);
  }
  #pragma unroll
  for (int j = 0; j < 4; ++j) {
    int r = wn + j * 16 + lm;
    offB[j] = r * 32 + (((kq + (r >> 1)) & 3) * 8);
  }

  f32x4 acc[8][4];
  #pragma unroll
  for (int i = 0; i < 8; ++i)
    #pragma unroll
    for (int j = 0; j < 4; ++j)
      acc[i][j] = (f32x4){0.f, 0.f, 0.f, 0.f};

  half8 a[4], b[4];

  // ---- prologue: stage buf0 {A,B}x{kh0,kh1} + buf1 {A,B} kh0 (12 loads) ----
  async_cp16(sA + g0,      lds + 0     + d0);  async_cp16(sA + g1,      lds + 0     + d1);
  async_cp16(sB + g0,      lds + 16384 + d0);  async_cp16(sB + g1,      lds + 16384 + d1);
  async_cp16(sA + g0 + 32, lds + 8192  + d0);  async_cp16(sA + g1 + 32, lds + 8192  + d1);
  async_cp16(sB + g0 + 32, lds + 24576 + d0);  async_cp16(sB + g1 + 32, lds + 24576 + d1);
  async_cp16(sA + g0 + 64, lds + 32768 + d0);  async_cp16(sA + g1 + 64, lds + 32768 + d1);
  async_cp16(sB + g0 + 64, lds + 49152 + d0);  async_cp16(sB + g1 + 64, lds + 49152 + d1);
  asm volatile("s_waitcnt vmcnt(4)" ::: "memory");   // buf0 fully landed; buf1-kh0 in flight
  // (first KTILE's P1 barrier completes the handoff)

  // ---- main loop: K = 1024 -> 16 K-tiles, 2 per unrolled iter ----
  for (int j2 = 0; j2 < 7; ++j2) {
    const int j = j2 * 2;
    KTILE(0, j,     1, 1, 4)
    KTILE(1, j + 1, 1, 1, 4)
  }
  KTILE(0, 14, 1, 0, 0)    // stages (15) kh1; drains everything
  KTILE(1, 15, 0, 0, -1)   // pure compute

  // ---- epilogue. C/D layout (m89-verified): col = lane&15, row = (lane>>4)*4 + reg ----
  const int cr = wm + (l >> 4) * 4;
  const int cc = wn + lm;
  if (EPI == 0) {
    float* C = (float*)C0;
    #pragma unroll
    for (int i = 0; i < 8; ++i)
      #pragma unroll
      for (int jj = 0; jj < 4; ++jj)
        #pragma unroll
        for (int r = 0; r < 4; ++r)
          C[(long)(m0 + cr + i * 16 + r) * 1024 + (n0 + cc + jj * 16)] = acc[i][jj][r];
  } else {
    unsigned short* C = (unsigned short*)C0;
    #pragma unroll
    for (int i = 0; i < 8; ++i)
      #pragma unroll
      for (int jj = 0; jj < 4; ++jj)
        #pragma unroll
        for (int r = 0; r < 4; ++r)
          C[(long)(m0 + cr + i * 16 + r) * 1024 + (n0 + cc + jj * 16)] = f2h(acc[i][jj][r]);
  }
}

// ---------- batched wrapper (QK^T, PV): fp32 C ----------
__global__ __launch_bounds__(512, 2)
void gemm_bt256(const unsigned short* __restrict__ A, const unsigned short* __restrict__ B,
                float* __restrict__ C, long aZ, long bZ, long cZ)
{
  __shared__ __align__(16) unsigned short lds[65536];   // 128 KiB
  // 256 blocks: bijective XCD-chunked swizzle (256 % 8 == 0) -> one batch per XCD
  const int bid = blockIdx.x;
  const int lin = (bid & 7) * 32 + (bid >> 3);
  const long z = lin >> 5;
  const int rr = lin & 31;
  gemm256_core<0>(A + z * aZ, B + z * bZ, (void*)(C + z * cZ),
                  (rr >> 2) * 256, (rr & 3) * 256, lds);
}

// ---------- merged projections: Qproj (256 blocks) + Kproj (128) + Vproj (128) ----------
__global__ __launch_bounds__(512, 2)
void proj_all256(const unsigned short* __restrict__ ch, const unsigned short* __restrict__ qh,
                 const unsigned short* __restrict__ wT,
                 unsigned short* __restrict__ Qf, unsigned short* __restrict__ Kf,
                 unsigned short* __restrict__ Vt)
{
  __shared__ __align__(16) unsigned short lds[65536];   // 128 KiB
  const int bid = blockIdx.x;
  const int lin = (bid & 7) * 64 + (bid >> 3);          // 512 % 8 == 0, bijective
  const long qBatch = 1024l * 1024;

  const unsigned short* pA;
  const unsigned short* pB;
  unsigned short* C;
  int m0, n0;
  if (lin < 256) {                  // Qproj: Q = c @ wq  [16384,1024]
    pA = ch; pB = wT; C = Qf;
    m0 = (lin >> 2) * 256; n0 = (lin & 3) * 256;
  } else if (lin < 384) {           // Kproj: K = q @ wk  [8192,1024]
    int i = lin - 256;
    pA = qh; pB = wT + (1l << 20); C = Kf;
    m0 = (i >> 2) * 256; n0 = (i & 3) * 256;
  } else {                          // Vproj: Vt[z][h,l] = wvT @ q[z]^T  [8][1024,1024]
    int i = lin - 384;
    long z = i >> 4;
    pA = wT + (2l << 20); pB = qh + z * qBatch; C = Vt + z * qBatch;
    m0 = ((i >> 2) & 3) * 256; n0 = (i & 3) * 256;
  }
  gemm256_core<1>(pA, pB, C, m0, n0, lds);
}

// ---------- merged prep: cvt_c (16384 blocks) + cvt_q (8192) + wtrans (3072) ----------
__global__ __launch_bounds__(256)
void prep_all(const float* __restrict__ q, const float* __restrict__ c,
              const float* __restrict__ wq, const float* __restrict__ wk,
              const float* __restrict__ wv,
              unsigned short* __restrict__ qh, unsigned short* __restrict__ ch,
              unsigned short* __restrict__ wT)
{
  __shared__ float tile[32][33];
  const int bid = blockIdx.x;
  const int t = threadIdx.x;

  if (bid < 24576) {                // fp32 -> fp16 convert, 1024 elems/block
    const float* x;
    unsigned short* y;
    long blk;
    if (bid < 16384) { x = c; y = ch; blk = bid; }
    else             { x = q; y = qh; blk = bid - 16384; }
    long i = (blk * 256 + t) * 4;
    float4 v = *(const float4*)(x + i);
    *(us4*)(y + i) = (us4){f2h(v.x), f2h(v.y), f2h(v.z), f2h(v.w)};
  } else {                          // weight transpose + convert
    int i = bid - 24576;
    const int d0 = (i & 31) * 32, h0 = ((i >> 5) & 31) * 32, id = i >> 10;
    const float* W = (id == 0) ? wq : ((id == 1) ? wk : wv);
    unsigned short* WT = wT + (long)id * (1 << 20);
    #pragma unroll
    for (int p = 0; p < 4; ++p) {
      int dl = p * 8 + (t >> 5), hl = t & 31;
      tile[dl][hl] = W[(long)(d0 + dl) * 1024 + h0 + hl];
    }
    __syncthreads();
    #pragma unroll
    for (int p = 0; p < 4; ++p) {
      int hr = p * 8 + (t >> 5), dc = t & 31;
      WT[(long)(h0 + hr) * 1024 + d0 + dc] = f2h(tile[dc][hr]);
    }
  }
}

// ---------- row softmax: S fp32 [rows,1024] -> P fp16 [rows,1024] ----------
__global__ __launch_bounds__(256)
void softmax_rows(const float* __restrict__ S, unsigned short* __restrict__ P)
{
  const long row = blockIdx.x;
  const int t = threadIdx.x;
  float4 v = *(const float4*)(S + row * 1024 + t * 4);
  float m = fmaxf(fmaxf(v.x, v.y), fmaxf(v.z, v.w));
  #pragma unroll
  for (int off = 32; off > 0; off >>= 1) m = fmaxf(m, __shfl_down(m, off));
  __shared__ float red[4], red2[4];
  if ((t & 63) == 0) red[t >> 6] = m;
  __syncthreads();
  m = fmaxf(fmaxf(red[0], red[1]), fmaxf(red[2], red[3]));
  float e0 = __expf(v.x - m), e1 = __expf(v.y - m);
  float e2 = __expf(v.z - m), e3 = __expf(v.w - m);
  float sum = e0 + e1 + e2 + e3;
  #pragma unroll
  for (int off = 32; off > 0; off >>= 1) sum += __shfl_down(sum, off);
  if ((t & 63) == 0) red2[t >> 6] = sum;
  __syncthreads();
  float inv = 1.0f / (red2[0] + red2[1] + red2[2] + red2[3]);
  us4 o = {f2h(e0 * inv), f2h(e1 * inv), f2h(e2 * inv), f2h(e3 * inv)};
  *(us4*)(P + row * 1024 + t * 4) = o;
}

// ---------- host ----------
extern "C" void kernel_launch(void* const* d_in, const int* in_sizes, int n_in,
                              void* d_out, int out_size, void* d_ws, size_t ws_size,
                              hipStream_t stream)
{
  (void)in_sizes; (void)n_in; (void)out_size; (void)ws_size;
  // inputs: q [8,1024,1024], c [8,2048,1024], wq, wk, wv [1024,1024], all fp32
  const float* q  = (const float*)d_in[0];
  const float* c  = (const float*)d_in[1];
  const float* wq = (const float*)d_in[2];
  const float* wk = (const float*)d_in[3];
  const float* wv = (const float*)d_in[4];
  float* out = (float*)d_out;   // [8, 2048, 1024]; also S scratch

  const size_t MB = 1ull << 20;
  const long cBatch = 2048l * 1024;   // c/Q/S/out elems per batch
  const long qBatch = 1024l * 1024;   // q/K/V elems per batch

  char* ws = (char*)d_ws;
  size_t off = 0;
  auto take = [&](size_t bytes) -> unsigned short* {
    unsigned short* p = (unsigned short*)(ws + off);
    off += bytes;
    return p;
  };
  // 118 MB total
  unsigned short* wT = take(6 * MB);    // 3x [1024(h),1024(d)] fp16: wqT, wkT, wvT
  unsigned short* qh = take(16 * MB);   // [8192,1024] fp16
  unsigned short* ch = take(32 * MB);   // [16384,1024] fp16; P aliases after Qproj
  unsigned short* Kf = take(16 * MB);   // [8192,1024] fp16
  unsigned short* Vt = take(16 * MB);   // [8][1024(h),1024(lq)] fp16
  unsigned short* Qf = take(32 * MB);   // [16384,1024] fp16
  unsigned short* Pf = ch;              // [16384,1024] fp16 (c-f16 dead after Qproj)

  // 1) prep: c->fp16, q->fp16, weights transpose->fp16
  prep_all<<<27648, 256, 0, stream>>>(q, c, wq, wk, wv, qh, ch, wT);
  // 2) all three projections, 256^2 single-barrier-phase core (512 blocks)
  proj_all256<<<512, 512, 0, stream>>>(ch, qh, wT, Qf, Kf, Vt);
  // 3) QK^T: S[c,qt] = sum_h Q[c,h] * K[qt,h]  (S fp32 in d_out region)
  gemm_bt256<<<256, 512, 0, stream>>>(Qf, Kf, out, cBatch, qBatch, cBatch);
  // 4) softmax rows -> P fp16
  softmax_rows<<<16384, 256, 0, stream>>>(out, Pf);
  // 5) PV: out[c,h] = sum_qt P[c,qt] * Vt[h,qt]
  gemm_bt256<<<256, 512, 0, stream>>>(Pf, Vt, out, cBatch, qBatch, cBatch);
}